// Round 8
// baseline (3116.501 us; speedup 1.0000x reference)
//
#include <hip/hip_runtime.h>
#include <hip/hip_bf16.h>
#include <cstdint>
#include <cstddef>

// GCN restructured:
//   conv1: agg RAW 3-dim features (16B/edge from L2-resident 1.6MB table), W1 AFTER agg.
//   conv2: agg h1s rows stored bf16 (256B/edge), W2 AFTER agg, relu+Wf+pool fused in GEMM.
// CSR ranges assigned by wave-aggregated atomicAdd (order-free), not an ordered scan.

#define HID 128

__device__ inline float bflo(unsigned u) { return __uint_as_float(u << 16); }
__device__ inline float bfhi(unsigned u) { return __uint_as_float(u & 0xffff0000u); }

__global__ void k_deg(const int* __restrict__ dst, int* __restrict__ deg, int E) {
    int e = blockIdx.x * 256 + threadIdx.x;
    if (e < E) atomicAdd(&deg[dst[e]], 1);
}

// off[i] = order-free contiguous range start; one atomic per wave.
__global__ void k_off(const int* __restrict__ deg, int* __restrict__ off,
                      int* __restrict__ cursor, int* __restrict__ total, int n) {
    int i = blockIdx.x * 256 + threadIdx.x;
    int lane = threadIdx.x & 63;
    int d = (i < n) ? deg[i] : 0;
    int p = d;
    #pragma unroll
    for (int o = 1; o < 64; o <<= 1) {
        int v = __shfl_up(p, o);
        if (lane >= o) p += v;
    }
    int base = 0;
    if (lane == 63) base = atomicAdd(total, p);   // p at lane63 = wave total
    base = __shfl(base, 63);
    int my = base + p - d;                         // exclusive within wave
    if (i < n) { off[i] = my; cursor[i] = my; }
}

__global__ void k_dinv(const int* __restrict__ deg, float* __restrict__ dinv, int n) {
    int i = blockIdx.x * 256 + threadIdx.x;
    if (i < n) dinv[i] = rsqrtf((float)(deg[i] + 1));
}

__global__ void k_fill(const int* __restrict__ src, const int* __restrict__ dst,
                       int* __restrict__ cursor, int* __restrict__ csr, int E) {
    int e = blockIdx.x * 256 + threadIdx.x;
    if (e < E) {
        int d = dst[e];
        int p = atomicAdd(&cursor[d], 1);
        csr[p] = src[e];
    }
}

// xs[i] = {x[i]*dinv[i] (3), dinv[i]}  — 16B/node, 1.6MB table (L2-resident)
__global__ void k_xs(const float* __restrict__ x, const float* __restrict__ dinv,
                     float4* __restrict__ xs, int n) {
    int i = blockIdx.x * 256 + threadIdx.x;
    if (i >= n) return;
    float di = dinv[i];
    xs[i] = make_float4(x[i * 3 + 0] * di, x[i * 3 + 1] * di, x[i * 3 + 2] * di, di);
}

// conv1 aggregation on 3-dim raw features: one THREAD per node, 4x unrolled.
__global__ void k_agg1(const float4* __restrict__ xs, const int* __restrict__ off,
                       const int* __restrict__ deg, const int* __restrict__ csr,
                       float4* __restrict__ agg1, int n) {
    int i = blockIdx.x * 256 + threadIdx.x;
    if (i >= n) return;
    int e0 = off[i], e1 = e0 + deg[i];
    float sx = 0.f, sy = 0.f, sz = 0.f;
    int e = e0;
    for (; e + 4 <= e1; e += 4) {
        int s0 = csr[e], s1 = csr[e + 1], s2 = csr[e + 2], s3 = csr[e + 3];
        float4 v0 = xs[s0], v1 = xs[s1], v2 = xs[s2], v3 = xs[s3];
        sx += v0.x + v1.x + v2.x + v3.x;
        sy += v0.y + v1.y + v2.y + v3.y;
        sz += v0.z + v1.z + v2.z + v3.z;
    }
    for (; e < e1; ++e) {
        float4 v = xs[csr[e]];
        sx += v.x; sy += v.y; sz += v.z;
    }
    float4 self = xs[i];
    float di = self.w;
    agg1[i] = make_float4((sx + self.x) * di, (sy + self.y) * di, (sz + self.z) * di, di);
}

// h1s[i] = bf16( relu(agg1[i].xyz @ W1 + b1) * dinv )  — wave per node, 2 cols/lane
__global__ __launch_bounds__(256) void k_h1(const float4* __restrict__ agg1,
                                            const float* __restrict__ W1,
                                            const float* __restrict__ b1,
                                            unsigned short* __restrict__ h1s, int n) {
    int wv = threadIdx.x >> 6;
    int lane = threadIdx.x & 63;
    int i = blockIdx.x * 4 + wv;
    if (i >= n) return;
    int c0 = lane * 2;
    float4 a = agg1[i];
    float h0 = fmaxf(a.x * W1[0 * HID + c0]     + a.y * W1[1 * HID + c0]     + a.z * W1[2 * HID + c0]     + b1[c0],     0.f) * a.w;
    float h1 = fmaxf(a.x * W1[0 * HID + c0 + 1] + a.y * W1[1 * HID + c0 + 1] + a.z * W1[2 * HID + c0 + 1] + b1[c0 + 1], 0.f) * a.w;
    __hip_bfloat16 q0 = __float2bfloat16(h0);
    __hip_bfloat16 q1 = __float2bfloat16(h1);
    ushort2 pk;
    pk.x = *(unsigned short*)&q0;
    pk.y = *(unsigned short*)&q1;
    *(ushort2*)&h1s[(size_t)i * HID + c0] = pk;
}

// conv2 aggregation over bf16 rows (256B each): wave per node, 32 lanes x 8B,
// 2 edges per step (half-waves), 4x unroll.
__global__ __launch_bounds__(256) void k_agg2(const unsigned short* __restrict__ h1s,
                                              const float* __restrict__ dinv,
                                              const int* __restrict__ off,
                                              const int* __restrict__ deg,
                                              const int* __restrict__ csr,
                                              float* __restrict__ g2, int n) {
    int wv = threadIdx.x >> 6;
    int lane = threadIdx.x & 63;
    int half = lane >> 5;
    int col = lane & 31;          // owns cols 4c..4c+3
    int node = blockIdx.x * 4 + wv;
    if (node >= n) return;
    int e0 = off[node], e1 = e0 + deg[node];
    float ax = 0.f, ay = 0.f, az = 0.f, aw = 0.f;

    for (int base = e0; base < e1; base += 64) {
        int m = e1 - base; if (m > 64) m = 64;
        int idx = (base + lane < e1) ? csr[base + lane] : 0;
        int j = 0;
        for (; j + 8 <= m; j += 8) {
            int s0 = __shfl(idx, j + 0 + half);
            int s1 = __shfl(idx, j + 2 + half);
            int s2 = __shfl(idx, j + 4 + half);
            int s3 = __shfl(idx, j + 6 + half);
            uint2 r0 = *(const uint2*)&h1s[(size_t)s0 * HID + col * 4];
            uint2 r1 = *(const uint2*)&h1s[(size_t)s1 * HID + col * 4];
            uint2 r2 = *(const uint2*)&h1s[(size_t)s2 * HID + col * 4];
            uint2 r3 = *(const uint2*)&h1s[(size_t)s3 * HID + col * 4];
            ax += bflo(r0.x) + bflo(r1.x) + bflo(r2.x) + bflo(r3.x);
            ay += bfhi(r0.x) + bfhi(r1.x) + bfhi(r2.x) + bfhi(r3.x);
            az += bflo(r0.y) + bflo(r1.y) + bflo(r2.y) + bflo(r3.y);
            aw += bfhi(r0.y) + bfhi(r1.y) + bfhi(r2.y) + bfhi(r3.y);
        }
        for (; j < m; j += 2) {
            int jj = j + half;
            if (jj < m) {
                int s = __shfl(idx, jj);
                uint2 r = *(const uint2*)&h1s[(size_t)s * HID + col * 4];
                ax += bflo(r.x); ay += bfhi(r.x);
                az += bflo(r.y); aw += bfhi(r.y);
            }
        }
    }
    ax += __shfl_down(ax, 32);
    ay += __shfl_down(ay, 32);
    az += __shfl_down(az, 32);
    aw += __shfl_down(aw, 32);

    if (half == 0) {
        uint2 r = *(const uint2*)&h1s[(size_t)node * HID + col * 4];
        float di = dinv[node];
        float4 o;
        o.x = (ax + bflo(r.x)) * di;
        o.y = (ay + bfhi(r.x)) * di;
        o.z = (az + bflo(r.y)) * di;
        o.w = (aw + bfhi(r.y)) * di;
        *(float4*)&g2[(size_t)node * HID + col * 4] = o;
    }
}

// h2 = relu(g2 @ W2 + b2); fused epilogue: pool += sum_rows h2 . Wf
__global__ __launch_bounds__(256) void k_gemm2b(const float* __restrict__ g2,
                                                const float* __restrict__ W,
                                                const float* __restrict__ b2,
                                                const float* __restrict__ Wf,
                                                float* __restrict__ pool, int n) {
    __shared__ float hl[64][16];
    __shared__ float wl[16][128];
    int tid = threadIdx.x;
    int r0 = blockIdx.x * 64;
    int tr = tid >> 5;
    int tc = tid & 31;
    float4 acc[8];
    #pragma unroll
    for (int r = 0; r < 8; ++r) acc[r] = make_float4(0.f, 0.f, 0.f, 0.f);

    for (int k0 = 0; k0 < HID; k0 += 16) {
        int lr = tid >> 2, lk = (tid & 3) * 4;
        float4 hv = make_float4(0.f, 0.f, 0.f, 0.f);
        if (r0 + lr < n) hv = *(const float4*)&g2[(size_t)(r0 + lr) * HID + k0 + lk];
        *(float4*)&hl[lr][lk] = hv;
        #pragma unroll
        for (int q = 0; q < 2; ++q) {
            int idx = tid + q * 256;
            int kr = idx >> 5, c4 = (idx & 31) * 4;
            *(float4*)&wl[kr][c4] = *(const float4*)&W[(size_t)(k0 + kr) * HID + c4];
        }
        __syncthreads();
        #pragma unroll
        for (int kk = 0; kk < 16; ++kk) {
            float4 w = *(const float4*)&wl[kk][tc * 4];
            #pragma unroll
            for (int r = 0; r < 8; ++r) {
                float hv2 = hl[tr * 8 + r][kk];
                acc[r].x += hv2 * w.x; acc[r].y += hv2 * w.y;
                acc[r].z += hv2 * w.z; acc[r].w += hv2 * w.w;
            }
        }
        __syncthreads();
    }
    float4 bb = *(const float4*)&b2[tc * 4];
    float4 wf = *(const float4*)&Wf[tc * 4];
    float d = 0.f;
    #pragma unroll
    for (int r = 0; r < 8; ++r) {
        int row = r0 + tr * 8 + r;
        if (row < n) {
            float hx = fmaxf(acc[r].x + bb.x, 0.f);
            float hy = fmaxf(acc[r].y + bb.y, 0.f);
            float hz = fmaxf(acc[r].z + bb.z, 0.f);
            float hw = fmaxf(acc[r].w + bb.w, 0.f);
            d += hx * wf.x + hy * wf.y + hz * wf.z + hw * wf.w;
        }
    }
    #pragma unroll
    for (int o = 16; o > 0; o >>= 1) d += __shfl_down(d, o, 32);
    if ((tid & 31) == 0) atomicAdd(pool, d);
}

__global__ void k_final(const float* __restrict__ pool, const float* __restrict__ bf,
                        float* __restrict__ out, float invn) {
    if (threadIdx.x == 0 && blockIdx.x == 0) out[0] = pool[0] * invn + bf[0];
}

extern "C" void kernel_launch(void* const* d_in, const int* in_sizes, int n_in,
                              void* d_out, int out_size, void* d_ws, size_t ws_size,
                              hipStream_t stream) {
    const float* x  = (const float*)d_in[0];
    const int*   ei = (const int*)d_in[1];
    const float* W1 = (const float*)d_in[2];
    const float* b1 = (const float*)d_in[3];
    const float* W2 = (const float*)d_in[4];
    const float* b2 = (const float*)d_in[5];
    const float* Wf = (const float*)d_in[6];
    const float* bf = (const float*)d_in[7];
    int n = in_sizes[0] / 3;
    int E = in_sizes[1] / 2;
    const int* src = ei;
    const int* dst = ei + E;

    char* w = (char*)d_ws;
    int*    deg    = (int*)(w + 0);                    // 400KB
    int*    off    = (int*)(w + (512ll << 10));        // 400KB
    int*    cursor = (int*)(w + (1024ll << 10));       // 400KB
    float*  dinv   = (float*)(w + (1536ll << 10));     // 400KB
    float*  pool   = (float*)(w + (2048ll << 10));     // 4B
    int*    total  = (int*)(w + (2048ll << 10) + 64);  // 4B
    int*    csr    = (int*)(w + (2560ll << 10));       // 6.4MB
    float4* xs     = (float4*)(w + (9ll << 20));       // 1.6MB
    float4* agg1   = (float4*)(w + (11ll << 20));      // 1.6MB
    unsigned short* h1s = (unsigned short*)(w + (13ll << 20)); // 25.6MB
    float*  g2     = (float*)(w + (39ll << 20));       // 51.2MB

    hipMemsetAsync(deg, 0, (size_t)n * sizeof(int), stream);
    hipMemsetAsync(pool, 0, 128, stream);   // pool + total

    k_deg<<<(E + 255) / 256, 256, 0, stream>>>(dst, deg, E);
    k_off<<<(n + 255) / 256, 256, 0, stream>>>(deg, off, cursor, total, n);
    k_dinv<<<(n + 255) / 256, 256, 0, stream>>>(deg, dinv, n);
    k_fill<<<(E + 255) / 256, 256, 0, stream>>>(src, dst, cursor, csr, E);

    k_xs<<<(n + 255) / 256, 256, 0, stream>>>(x, dinv, xs, n);
    k_agg1<<<(n + 255) / 256, 256, 0, stream>>>(xs, off, deg, csr, agg1, n);
    k_h1<<<(n + 3) / 4, 256, 0, stream>>>(agg1, W1, b1, h1s, n);
    k_agg2<<<(n + 3) / 4, 256, 0, stream>>>(h1s, dinv, off, deg, csr, g2, n);
    k_gemm2b<<<(n + 63) / 64, 256, 0, stream>>>(g2, W2, b2, Wf, pool, n);
    k_final<<<1, 64, 0, stream>>>(pool, bf, (float*)d_out, 1.0f / (float)n);
}

// Round 10
// 484.500 us; speedup vs baseline: 6.4324x; 6.4324x over previous
//
#include <hip/hip_runtime.h>
#include <hip/hip_bf16.h>
#include <cstdint>
#include <cstddef>

// GCN restructured:
//   conv1: agg RAW 3-dim features (16B/edge from L2-resident 1.6MB table), W1 AFTER agg.
//   conv2: agg h1s rows stored bf16 (256B/edge), W2 AFTER agg, relu+Wf+pool fused in GEMM.
// CSR ranges via wave-aggregated atomicAdd (order-free). k_off also emits dinv + xs.

#define HID 128

__device__ inline float bflo(unsigned u) { return __uint_as_float(u << 16); }
__device__ inline float bfhi(unsigned u) { return __uint_as_float(u & 0xffff0000u); }

__global__ void k_deg(const int* __restrict__ dst, int* __restrict__ deg, int E) {
    int e = blockIdx.x * 256 + threadIdx.x;
    if (e < E) atomicAdd(&deg[dst[e]], 1);
}

// off[i] = order-free contiguous range start (one atomic per wave);
// also dinv[i] = rsqrt(deg+1) and xs[i] = {x*dinv, dinv}.
__global__ void k_off(const int* __restrict__ deg, const float* __restrict__ x,
                      int* __restrict__ off, int* __restrict__ cursor,
                      float* __restrict__ dinv, float4* __restrict__ xs,
                      int* __restrict__ total, int n) {
    int i = blockIdx.x * 256 + threadIdx.x;
    int lane = threadIdx.x & 63;
    int d = (i < n) ? deg[i] : 0;
    int p = d;
    #pragma unroll
    for (int o = 1; o < 64; o <<= 1) {
        int v = __shfl_up(p, o);
        if (lane >= o) p += v;
    }
    int base = 0;
    if (lane == 63) base = atomicAdd(total, p);   // p at lane63 = wave total
    base = __shfl(base, 63);
    int my = base + p - d;                         // exclusive within wave
    if (i < n) {
        off[i] = my; cursor[i] = my;
        float di = rsqrtf((float)(d + 1));
        dinv[i] = di;
        xs[i] = make_float4(x[i * 3 + 0] * di, x[i * 3 + 1] * di, x[i * 3 + 2] * di, di);
    }
}

__global__ void k_fill(const int* __restrict__ src, const int* __restrict__ dst,
                       int* __restrict__ cursor, int* __restrict__ csr, int E) {
    int e = blockIdx.x * 256 + threadIdx.x;
    if (e < E) {
        int d = dst[e];
        int p = atomicAdd(&cursor[d], 1);
        csr[p] = src[e];
    }
}

// conv1 aggregation on 3-dim raw features: one THREAD per node, 4x unrolled.
__global__ void k_agg1(const float4* __restrict__ xs, const int* __restrict__ off,
                       const int* __restrict__ deg, const int* __restrict__ csr,
                       float4* __restrict__ agg1, int n) {
    int i = blockIdx.x * 256 + threadIdx.x;
    if (i >= n) return;
    int e0 = off[i], e1 = e0 + deg[i];
    float sx = 0.f, sy = 0.f, sz = 0.f;
    int e = e0;
    for (; e + 4 <= e1; e += 4) {
        int s0 = csr[e], s1 = csr[e + 1], s2 = csr[e + 2], s3 = csr[e + 3];
        float4 v0 = xs[s0], v1 = xs[s1], v2 = xs[s2], v3 = xs[s3];
        sx += v0.x + v1.x + v2.x + v3.x;
        sy += v0.y + v1.y + v2.y + v3.y;
        sz += v0.z + v1.z + v2.z + v3.z;
    }
    for (; e < e1; ++e) {
        float4 v = xs[csr[e]];
        sx += v.x; sy += v.y; sz += v.z;
    }
    float4 self = xs[i];
    float di = self.w;
    agg1[i] = make_float4((sx + self.x) * di, (sy + self.y) * di, (sz + self.z) * di, di);
}

// h1s[i] = bf16( relu(agg1[i].xyz @ W1 + b1) * dinv )  — wave per node, 2 cols/lane
__global__ __launch_bounds__(256) void k_h1(const float4* __restrict__ agg1,
                                            const float* __restrict__ W1,
                                            const float* __restrict__ b1,
                                            unsigned short* __restrict__ h1s, int n) {
    int wv = threadIdx.x >> 6;
    int lane = threadIdx.x & 63;
    int i = blockIdx.x * 4 + wv;
    if (i >= n) return;
    int c0 = lane * 2;
    float4 a = agg1[i];
    float h0 = fmaxf(a.x * W1[0 * HID + c0]     + a.y * W1[1 * HID + c0]     + a.z * W1[2 * HID + c0]     + b1[c0],     0.f) * a.w;
    float h1 = fmaxf(a.x * W1[0 * HID + c0 + 1] + a.y * W1[1 * HID + c0 + 1] + a.z * W1[2 * HID + c0 + 1] + b1[c0 + 1], 0.f) * a.w;
    __hip_bfloat16 q0 = __float2bfloat16(h0);
    __hip_bfloat16 q1 = __float2bfloat16(h1);
    ushort2 pk;
    pk.x = *(unsigned short*)&q0;
    pk.y = *(unsigned short*)&q1;
    *(ushort2*)&h1s[(size_t)i * HID + c0] = pk;
}

// conv2 aggregation over bf16 rows (256B each): wave per node, 32 lanes x 8B,
// 2 edges per step (half-waves), 4x unroll.
__global__ __launch_bounds__(256) void k_agg2(const unsigned short* __restrict__ h1s,
                                              const float* __restrict__ dinv,
                                              const int* __restrict__ off,
                                              const int* __restrict__ deg,
                                              const int* __restrict__ csr,
                                              float* __restrict__ g2, int n) {
    int wv = threadIdx.x >> 6;
    int lane = threadIdx.x & 63;
    int half = lane >> 5;
    int col = lane & 31;          // owns cols 4c..4c+3
    int node = blockIdx.x * 4 + wv;
    if (node >= n) return;
    int e0 = off[node], e1 = e0 + deg[node];
    float ax = 0.f, ay = 0.f, az = 0.f, aw = 0.f;

    for (int base = e0; base < e1; base += 64) {
        int m = e1 - base; if (m > 64) m = 64;
        int idx = (base + lane < e1) ? csr[base + lane] : 0;
        int j = 0;
        for (; j + 8 <= m; j += 8) {
            int s0 = __shfl(idx, j + 0 + half);
            int s1 = __shfl(idx, j + 2 + half);
            int s2 = __shfl(idx, j + 4 + half);
            int s3 = __shfl(idx, j + 6 + half);
            uint2 r0 = *(const uint2*)&h1s[(size_t)s0 * HID + col * 4];
            uint2 r1 = *(const uint2*)&h1s[(size_t)s1 * HID + col * 4];
            uint2 r2 = *(const uint2*)&h1s[(size_t)s2 * HID + col * 4];
            uint2 r3 = *(const uint2*)&h1s[(size_t)s3 * HID + col * 4];
            ax += bflo(r0.x) + bflo(r1.x) + bflo(r2.x) + bflo(r3.x);
            ay += bfhi(r0.x) + bfhi(r1.x) + bfhi(r2.x) + bfhi(r3.x);
            az += bflo(r0.y) + bflo(r1.y) + bflo(r2.y) + bflo(r3.y);
            aw += bfhi(r0.y) + bfhi(r1.y) + bfhi(r2.y) + bfhi(r3.y);
        }
        for (; j < m; j += 2) {
            int jj = j + half;
            if (jj < m) {
                int s = __shfl(idx, jj);
                uint2 r = *(const uint2*)&h1s[(size_t)s * HID + col * 4];
                ax += bflo(r.x); ay += bfhi(r.x);
                az += bflo(r.y); aw += bfhi(r.y);
            }
        }
    }
    ax += __shfl_down(ax, 32);
    ay += __shfl_down(ay, 32);
    az += __shfl_down(az, 32);
    aw += __shfl_down(aw, 32);

    if (half == 0) {
        uint2 r = *(const uint2*)&h1s[(size_t)node * HID + col * 4];
        float di = dinv[node];
        float4 o;
        o.x = (ax + bflo(r.x)) * di;
        o.y = (ay + bfhi(r.x)) * di;
        o.z = (az + bflo(r.y)) * di;
        o.w = (aw + bfhi(r.y)) * di;
        *(float4*)&g2[(size_t)node * HID + col * 4] = o;
    }
}

// h2 = relu(g2 @ W2 + b2); fused epilogue: pool += sum_rows h2 . Wf
__global__ __launch_bounds__(256) void k_gemm2b(const float* __restrict__ g2,
                                                const float* __restrict__ W,
                                                const float* __restrict__ b2,
                                                const float* __restrict__ Wf,
                                                float* __restrict__ pool, int n) {
    __shared__ float hl[64][16];
    __shared__ float wl[16][128];
    int tid = threadIdx.x;
    int r0 = blockIdx.x * 64;
    int tr = tid >> 5;
    int tc = tid & 31;
    float4 acc[8];
    #pragma unroll
    for (int r = 0; r < 8; ++r) acc[r] = make_float4(0.f, 0.f, 0.f, 0.f);

    for (int k0 = 0; k0 < HID; k0 += 16) {
        int lr = tid >> 2, lk = (tid & 3) * 4;
        float4 hv = make_float4(0.f, 0.f, 0.f, 0.f);
        if (r0 + lr < n) hv = *(const float4*)&g2[(size_t)(r0 + lr) * HID + k0 + lk];
        *(float4*)&hl[lr][lk] = hv;
        #pragma unroll
        for (int q = 0; q < 2; ++q) {
            int idx = tid + q * 256;
            int kr = idx >> 5, c4 = (idx & 31) * 4;
            *(float4*)&wl[kr][c4] = *(const float4*)&W[(size_t)(k0 + kr) * HID + c4];
        }
        __syncthreads();
        #pragma unroll
        for (int kk = 0; kk < 16; ++kk) {
            float4 w = *(const float4*)&wl[kk][tc * 4];
            #pragma unroll
            for (int r = 0; r < 8; ++r) {
                float hv2 = hl[tr * 8 + r][kk];
                acc[r].x += hv2 * w.x; acc[r].y += hv2 * w.y;
                acc[r].z += hv2 * w.z; acc[r].w += hv2 * w.w;
            }
        }
        __syncthreads();
    }
    float4 bb = *(const float4*)&b2[tc * 4];
    float4 wf = *(const float4*)&Wf[tc * 4];
    float d = 0.f;
    #pragma unroll
    for (int r = 0; r < 8; ++r) {
        int row = r0 + tr * 8 + r;
        if (row < n) {
            float hx = fmaxf(acc[r].x + bb.x, 0.f);
            float hy = fmaxf(acc[r].y + bb.y, 0.f);
            float hz = fmaxf(acc[r].z + bb.z, 0.f);
            float hw = fmaxf(acc[r].w + bb.w, 0.f);
            d += hx * wf.x + hy * wf.y + hz * wf.z + hw * wf.w;
        }
    }
    #pragma unroll
    for (int o = 16; o > 0; o >>= 1) d += __shfl_down(d, o, 32);
    if ((tid & 31) == 0) atomicAdd(pool, d);
}

__global__ void k_final(const float* __restrict__ pool, const float* __restrict__ bf,
                        float* __restrict__ out, float invn) {
    if (threadIdx.x == 0 && blockIdx.x == 0) out[0] = pool[0] * invn + bf[0];
}

extern "C" void kernel_launch(void* const* d_in, const int* in_sizes, int n_in,
                              void* d_out, int out_size, void* d_ws, size_t ws_size,
                              hipStream_t stream) {
    const float* x  = (const float*)d_in[0];
    const int*   ei = (const int*)d_in[1];
    const float* W1 = (const float*)d_in[2];
    const float* b1 = (const float*)d_in[3];
    const float* W2 = (const float*)d_in[4];
    const float* b2 = (const float*)d_in[5];
    const float* Wf = (const float*)d_in[6];
    const float* bf = (const float*)d_in[7];
    int n = in_sizes[0] / 3;
    int E = in_sizes[1] / 2;
    const int* src = ei;
    const int* dst = ei + E;

    char* w = (char*)d_ws;
    int*    deg    = (int*)(w + 0);                    // 400KB
    int*    off    = (int*)(w + (512ll << 10));        // 400KB
    int*    cursor = (int*)(w + (1024ll << 10));       // 400KB
    float*  dinv   = (float*)(w + (1536ll << 10));     // 400KB
    float*  pool   = (float*)(w + (2048ll << 10));     // 4B
    int*    total  = (int*)(w + (2048ll << 10) + 64);  // 4B
    int*    csr    = (int*)(w + (2560ll << 10));       // 6.4MB
    float4* xs     = (float4*)(w + (9ll << 20));       // 1.6MB
    float4* agg1   = (float4*)(w + (11ll << 20));      // 1.6MB
    unsigned short* h1s = (unsigned short*)(w + (13ll << 20)); // 25.6MB
    float*  g2     = (float*)(w + (39ll << 20));       // 51.2MB

    hipMemsetAsync(deg, 0, (size_t)n * sizeof(int), stream);
    hipMemsetAsync(pool, 0, 128, stream);   // pool + total

    k_deg<<<(E + 255) / 256, 256, 0, stream>>>(dst, deg, E);
    k_off<<<(n + 255) / 256, 256, 0, stream>>>(deg, x, off, cursor, dinv, xs, total, n);
    k_fill<<<(E + 255) / 256, 256, 0, stream>>>(src, dst, cursor, csr, E);

    k_agg1<<<(n + 255) / 256, 256, 0, stream>>>(xs, off, deg, csr, agg1, n);
    k_h1<<<(n + 3) / 4, 256, 0, stream>>>(agg1, W1, b1, h1s, n);
    k_agg2<<<(n + 3) / 4, 256, 0, stream>>>(h1s, dinv, off, deg, csr, g2, n);
    k_gemm2b<<<(n + 63) / 64, 256, 0, stream>>>(g2, W2, b2, Wf, pool, n);
    k_final<<<1, 64, 0, stream>>>(pool, bf, (float*)d_out, 1.0f / (float)n);
}

// Round 11
// 461.607 us; speedup vs baseline: 6.7514x; 1.0496x over previous
//
#include <hip/hip_runtime.h>
#include <hip/hip_bf16.h>
#include <cstdint>
#include <cstddef>

// GCN restructured:
//   conv1: agg RAW 3-dim features, W1 AFTER agg.  conv2: agg bf16 h1s rows, W2 AFTER agg,
//   relu+Wf+pool fused into the GEMM epilogue.
// CSR build is dst-WINDOWED (8 windows, one per XCD via blockIdx&7) so scatter writes
// stay in one XCD's L2 and lines absorb all ~deg writes before flushing once.

#define HID 128
#define NWIN 8

__device__ inline float bflo(unsigned u) { return __uint_as_float(u << 16); }
__device__ inline float bfhi(unsigned u) { return __uint_as_float(u & 0xffff0000u); }

// degree count + per-window edge histogram
__global__ void k_deg(const int* __restrict__ dst, int* __restrict__ deg,
                      int* __restrict__ wintot, int E, int nper) {
    __shared__ int h[NWIN];
    if (threadIdx.x < NWIN) h[threadIdx.x] = 0;
    __syncthreads();
    int e = blockIdx.x * 256 + threadIdx.x;
    if (e < E) {
        int d = dst[e];
        atomicAdd(&deg[d], 1);
        atomicAdd(&h[d / nper], 1);
    }
    __syncthreads();
    if (threadIdx.x < NWIN) atomicAdd(&wintot[threadIdx.x], h[threadIdx.x]);
}

// tiny ordered scan of the 8 window totals -> window base cursors
__global__ void k_winscan(const int* __restrict__ wintot, int* __restrict__ wincur) {
    int t = threadIdx.x;
    int v = (t < NWIN) ? wintot[t] : 0;
    int p = v;
    #pragma unroll
    for (int o = 1; o < NWIN; o <<= 1) {
        int u = __shfl_up(p, o);
        if (t >= o) p += u;
    }
    if (t < NWIN) wincur[t] = p - v;   // exclusive prefix
}

// node range start within its window (order-free, one atomic per wave);
// also dinv[i] and xs[i] = {x*dinv, dinv}.  nper % 64 == 0 => wave-uniform window.
__global__ void k_off(const int* __restrict__ deg, const float* __restrict__ x,
                      int* __restrict__ off, int* __restrict__ cursor,
                      float* __restrict__ dinv, float4* __restrict__ xs,
                      int* __restrict__ wincur, int n, int nper) {
    int i = blockIdx.x * 256 + threadIdx.x;
    int lane = threadIdx.x & 63;
    int d = (i < n) ? deg[i] : 0;
    int win = (i < n) ? (i / nper) : (NWIN - 1);
    int p = d;
    #pragma unroll
    for (int o = 1; o < 64; o <<= 1) {
        int v = __shfl_up(p, o);
        if (lane >= o) p += v;
    }
    int base = 0;
    if (lane == 63) base = atomicAdd(&wincur[win], p);
    base = __shfl(base, 63);
    int my = base + p - d;
    if (i < n) {
        off[i] = my; cursor[i] = my;
        float di = rsqrtf((float)(d + 1));
        dinv[i] = di;
        xs[i] = make_float4(x[i * 3 + 0] * di, x[i * 3 + 1] * di, x[i * 3 + 2] * di, di);
    }
}

// windowed CSR fill: window = blockIdx&7 (XCD round-robin heuristic); each window-set
// grid-strides all edges, keeps only dst in its window -> csr writes L2-local.
__global__ __launch_bounds__(256) void k_fill(const int* __restrict__ src,
                                              const int* __restrict__ dst,
                                              int* __restrict__ cursor,
                                              int* __restrict__ csr, int E, int nper) {
    int win = blockIdx.x & (NWIN - 1);
    int nblk = gridDim.x >> 3;
    int bw = blockIdx.x >> 3;
    int lo = win * nper, hi = lo + nper;
    for (int e = bw * 256 + threadIdx.x; e < E; e += nblk * 256) {
        int d = dst[e];
        if (d >= lo && d < hi) {
            int p = atomicAdd(&cursor[d], 1);
            csr[p] = src[e];
        }
    }
}

// conv1 aggregation on 3-dim raw features: one THREAD per node, 4x unrolled.
__global__ void k_agg1(const float4* __restrict__ xs, const int* __restrict__ off,
                       const int* __restrict__ deg, const int* __restrict__ csr,
                       float4* __restrict__ agg1, int n) {
    int i = blockIdx.x * 256 + threadIdx.x;
    if (i >= n) return;
    int e0 = off[i], e1 = e0 + deg[i];
    float sx = 0.f, sy = 0.f, sz = 0.f;
    int e = e0;
    for (; e + 4 <= e1; e += 4) {
        int s0 = csr[e], s1 = csr[e + 1], s2 = csr[e + 2], s3 = csr[e + 3];
        float4 v0 = xs[s0], v1 = xs[s1], v2 = xs[s2], v3 = xs[s3];
        sx += v0.x + v1.x + v2.x + v3.x;
        sy += v0.y + v1.y + v2.y + v3.y;
        sz += v0.z + v1.z + v2.z + v3.z;
    }
    for (; e < e1; ++e) {
        float4 v = xs[csr[e]];
        sx += v.x; sy += v.y; sz += v.z;
    }
    float4 self = xs[i];
    float di = self.w;
    agg1[i] = make_float4((sx + self.x) * di, (sy + self.y) * di, (sz + self.z) * di, di);
}

// h1s[i] = bf16( relu(agg1[i].xyz @ W1 + b1) * dinv )  — wave per node, 2 cols/lane
__global__ __launch_bounds__(256) void k_h1(const float4* __restrict__ agg1,
                                            const float* __restrict__ W1,
                                            const float* __restrict__ b1,
                                            unsigned short* __restrict__ h1s, int n) {
    int wv = threadIdx.x >> 6;
    int lane = threadIdx.x & 63;
    int i = blockIdx.x * 4 + wv;
    if (i >= n) return;
    int c0 = lane * 2;
    float4 a = agg1[i];
    float h0 = fmaxf(a.x * W1[0 * HID + c0]     + a.y * W1[1 * HID + c0]     + a.z * W1[2 * HID + c0]     + b1[c0],     0.f) * a.w;
    float h1 = fmaxf(a.x * W1[0 * HID + c0 + 1] + a.y * W1[1 * HID + c0 + 1] + a.z * W1[2 * HID + c0 + 1] + b1[c0 + 1], 0.f) * a.w;
    __hip_bfloat16 q0 = __float2bfloat16(h0);
    __hip_bfloat16 q1 = __float2bfloat16(h1);
    ushort2 pk;
    pk.x = *(unsigned short*)&q0;
    pk.y = *(unsigned short*)&q1;
    *(ushort2*)&h1s[(size_t)i * HID + c0] = pk;
}

// conv2 aggregation over bf16 rows (256B each): wave per node, 32 lanes x 8B,
// 2 edges per step (half-waves), 4x unroll.
__global__ __launch_bounds__(256) void k_agg2(const unsigned short* __restrict__ h1s,
                                              const float* __restrict__ dinv,
                                              const int* __restrict__ off,
                                              const int* __restrict__ deg,
                                              const int* __restrict__ csr,
                                              float* __restrict__ g2, int n) {
    int wv = threadIdx.x >> 6;
    int lane = threadIdx.x & 63;
    int half = lane >> 5;
    int col = lane & 31;
    int node = blockIdx.x * 4 + wv;
    if (node >= n) return;
    int e0 = off[node], e1 = e0 + deg[node];
    float ax = 0.f, ay = 0.f, az = 0.f, aw = 0.f;

    for (int base = e0; base < e1; base += 64) {
        int m = e1 - base; if (m > 64) m = 64;
        int idx = (base + lane < e1) ? csr[base + lane] : 0;
        int j = 0;
        for (; j + 8 <= m; j += 8) {
            int s0 = __shfl(idx, j + 0 + half);
            int s1 = __shfl(idx, j + 2 + half);
            int s2 = __shfl(idx, j + 4 + half);
            int s3 = __shfl(idx, j + 6 + half);
            uint2 r0 = *(const uint2*)&h1s[(size_t)s0 * HID + col * 4];
            uint2 r1 = *(const uint2*)&h1s[(size_t)s1 * HID + col * 4];
            uint2 r2 = *(const uint2*)&h1s[(size_t)s2 * HID + col * 4];
            uint2 r3 = *(const uint2*)&h1s[(size_t)s3 * HID + col * 4];
            ax += bflo(r0.x) + bflo(r1.x) + bflo(r2.x) + bflo(r3.x);
            ay += bfhi(r0.x) + bfhi(r1.x) + bfhi(r2.x) + bfhi(r3.x);
            az += bflo(r0.y) + bflo(r1.y) + bflo(r2.y) + bflo(r3.y);
            aw += bfhi(r0.y) + bfhi(r1.y) + bfhi(r2.y) + bfhi(r3.y);
        }
        for (; j < m; j += 2) {
            int jj = j + half;
            if (jj < m) {
                int s = __shfl(idx, jj);
                uint2 r = *(const uint2*)&h1s[(size_t)s * HID + col * 4];
                ax += bflo(r.x); ay += bfhi(r.x);
                az += bflo(r.y); aw += bfhi(r.y);
            }
        }
    }
    ax += __shfl_down(ax, 32);
    ay += __shfl_down(ay, 32);
    az += __shfl_down(az, 32);
    aw += __shfl_down(aw, 32);

    if (half == 0) {
        uint2 r = *(const uint2*)&h1s[(size_t)node * HID + col * 4];
        float di = dinv[node];
        float4 o;
        o.x = (ax + bflo(r.x)) * di;
        o.y = (ay + bfhi(r.x)) * di;
        o.z = (az + bflo(r.y)) * di;
        o.w = (aw + bfhi(r.y)) * di;
        *(float4*)&g2[(size_t)node * HID + col * 4] = o;
    }
}

// h2 = relu(g2 @ W2 + b2); fused epilogue: pool += sum_rows h2 . Wf
__global__ __launch_bounds__(256) void k_gemm2b(const float* __restrict__ g2,
                                                const float* __restrict__ W,
                                                const float* __restrict__ b2,
                                                const float* __restrict__ Wf,
                                                float* __restrict__ pool, int n) {
    __shared__ float hl[64][16];
    __shared__ float wl[16][128];
    int tid = threadIdx.x;
    int r0 = blockIdx.x * 64;
    int tr = tid >> 5;
    int tc = tid & 31;
    float4 acc[8];
    #pragma unroll
    for (int r = 0; r < 8; ++r) acc[r] = make_float4(0.f, 0.f, 0.f, 0.f);

    for (int k0 = 0; k0 < HID; k0 += 16) {
        int lr = tid >> 2, lk = (tid & 3) * 4;
        float4 hv = make_float4(0.f, 0.f, 0.f, 0.f);
        if (r0 + lr < n) hv = *(const float4*)&g2[(size_t)(r0 + lr) * HID + k0 + lk];
        *(float4*)&hl[lr][lk] = hv;
        #pragma unroll
        for (int q = 0; q < 2; ++q) {
            int idx = tid + q * 256;
            int kr = idx >> 5, c4 = (idx & 31) * 4;
            *(float4*)&wl[kr][c4] = *(const float4*)&W[(size_t)(k0 + kr) * HID + c4];
        }
        __syncthreads();
        #pragma unroll
        for (int kk = 0; kk < 16; ++kk) {
            float4 w = *(const float4*)&wl[kk][tc * 4];
            #pragma unroll
            for (int r = 0; r < 8; ++r) {
                float hv2 = hl[tr * 8 + r][kk];
                acc[r].x += hv2 * w.x; acc[r].y += hv2 * w.y;
                acc[r].z += hv2 * w.z; acc[r].w += hv2 * w.w;
            }
        }
        __syncthreads();
    }
    float4 bb = *(const float4*)&b2[tc * 4];
    float4 wf = *(const float4*)&Wf[tc * 4];
    float d = 0.f;
    #pragma unroll
    for (int r = 0; r < 8; ++r) {
        int row = r0 + tr * 8 + r;
        if (row < n) {
            float hx = fmaxf(acc[r].x + bb.x, 0.f);
            float hy = fmaxf(acc[r].y + bb.y, 0.f);
            float hz = fmaxf(acc[r].z + bb.z, 0.f);
            float hw = fmaxf(acc[r].w + bb.w, 0.f);
            d += hx * wf.x + hy * wf.y + hz * wf.z + hw * wf.w;
        }
    }
    #pragma unroll
    for (int o = 16; o > 0; o >>= 1) d += __shfl_down(d, o, 32);
    if ((tid & 31) == 0) atomicAdd(pool, d);
}

__global__ void k_final(const float* __restrict__ pool, const float* __restrict__ bf,
                        float* __restrict__ out, float invn) {
    if (threadIdx.x == 0 && blockIdx.x == 0) out[0] = pool[0] * invn + bf[0];
}

extern "C" void kernel_launch(void* const* d_in, const int* in_sizes, int n_in,
                              void* d_out, int out_size, void* d_ws, size_t ws_size,
                              hipStream_t stream) {
    const float* x  = (const float*)d_in[0];
    const int*   ei = (const int*)d_in[1];
    const float* W1 = (const float*)d_in[2];
    const float* b1 = (const float*)d_in[3];
    const float* W2 = (const float*)d_in[4];
    const float* b2 = (const float*)d_in[5];
    const float* Wf = (const float*)d_in[6];
    const float* bf = (const float*)d_in[7];
    int n = in_sizes[0] / 3;
    int E = in_sizes[1] / 2;
    const int* src = ei;
    const int* dst = ei + E;
    int nper = ((n + NWIN - 1) / NWIN + 63) & ~63;   // window size, multiple of 64

    char* w = (char*)d_ws;
    int*    deg    = (int*)(w + 0);                    // 400KB
    int*    off    = (int*)(w + (512ll << 10));        // 400KB
    int*    cursor = (int*)(w + (1024ll << 10));       // 400KB
    float*  dinv   = (float*)(w + (1536ll << 10));     // 400KB
    float*  pool   = (float*)(w + (2048ll << 10));     // 4B
    int*    wintot = (int*)(w + (2048ll << 10) + 128); // 32B
    int*    wincur = (int*)(w + (2048ll << 10) + 256); // 32B
    int*    csr    = (int*)(w + (2560ll << 10));       // 6.4MB
    float4* xs     = (float4*)(w + (9ll << 20));       // 1.6MB
    float4* agg1   = (float4*)(w + (11ll << 20));      // 1.6MB
    unsigned short* h1s = (unsigned short*)(w + (13ll << 20)); // 25.6MB
    float*  g2     = (float*)(w + (39ll << 20));       // 51.2MB

    hipMemsetAsync(deg, 0, (size_t)n * sizeof(int), stream);
    hipMemsetAsync(pool, 0, 512, stream);   // pool + wintot + wincur

    k_deg<<<(E + 255) / 256, 256, 0, stream>>>(dst, deg, wintot, E, nper);
    k_winscan<<<1, 64, 0, stream>>>(wintot, wincur);
    k_off<<<(n + 255) / 256, 256, 0, stream>>>(deg, x, off, cursor, dinv, xs, wincur, n, nper);
    k_fill<<<1024, 256, 0, stream>>>(src, dst, cursor, csr, E, nper);

    k_agg1<<<(n + 255) / 256, 256, 0, stream>>>(xs, off, deg, csr, agg1, n);
    k_h1<<<(n + 3) / 4, 256, 0, stream>>>(agg1, W1, b1, h1s, n);
    k_agg2<<<(n + 3) / 4, 256, 0, stream>>>(h1s, dinv, off, deg, csr, g2, n);
    k_gemm2b<<<(n + 63) / 64, 256, 0, stream>>>(g2, W2, b2, Wf, pool, n);
    k_final<<<1, 64, 0, stream>>>(pool, bf, (float*)d_out, 1.0f / (float)n);
}

// Round 12
// 460.016 us; speedup vs baseline: 6.7748x; 1.0035x over previous
//
#include <hip/hip_runtime.h>
#include <hip/hip_bf16.h>
#include <cstdint>
#include <cstddef>

// GCN restructured:
//   conv1: agg RAW 3-dim features, W1 AFTER agg.  conv2: agg bf16 h1s rows -> bf16 g2s,
//   then MFMA bf16 GEMM (g2s @ W2) with relu+Wf+pool fused in the epilogue.
// CSR build is dst-WINDOWED (8 windows via blockIdx&7) for L2-local scatter.

#define HID 128
#define NWIN 8

typedef short bf16x8 __attribute__((ext_vector_type(8)));
typedef float f32x4 __attribute__((ext_vector_type(4)));

__device__ inline float bflo(unsigned u) { return __uint_as_float(u << 16); }
__device__ inline float bfhi(unsigned u) { return __uint_as_float(u & 0xffff0000u); }
__device__ inline unsigned short f2bf(float f) {
    __hip_bfloat16 q = __float2bfloat16(f);
    return *(unsigned short*)&q;
}

// degree count + per-window edge histogram
__global__ void k_deg(const int* __restrict__ dst, int* __restrict__ deg,
                      int* __restrict__ wintot, int E, int nper) {
    __shared__ int h[NWIN];
    if (threadIdx.x < NWIN) h[threadIdx.x] = 0;
    __syncthreads();
    int e = blockIdx.x * 256 + threadIdx.x;
    if (e < E) {
        int d = dst[e];
        atomicAdd(&deg[d], 1);
        atomicAdd(&h[d / nper], 1);
    }
    __syncthreads();
    if (threadIdx.x < NWIN) atomicAdd(&wintot[threadIdx.x], h[threadIdx.x]);
}

__global__ void k_winscan(const int* __restrict__ wintot, int* __restrict__ wincur) {
    int t = threadIdx.x;
    int v = (t < NWIN) ? wintot[t] : 0;
    int p = v;
    #pragma unroll
    for (int o = 1; o < NWIN; o <<= 1) {
        int u = __shfl_up(p, o);
        if (t >= o) p += u;
    }
    if (t < NWIN) wincur[t] = p - v;
}

// W2T[c][k] = bf16(W2[k][c])  (32KB, built once, L2-resident)
__global__ void k_w2t(const float* __restrict__ W2, unsigned short* __restrict__ W2T) {
    int i = blockIdx.x * 256 + threadIdx.x;
    if (i < HID * HID) {
        int k = i >> 7, c = i & 127;
        W2T[c * HID + k] = f2bf(W2[k * HID + c]);
    }
}

// node range start within its window (order-free, one atomic per wave);
// also dinv[i] and xs[i] = {x*dinv, dinv}.
__global__ void k_off(const int* __restrict__ deg, const float* __restrict__ x,
                      int* __restrict__ off, int* __restrict__ cursor,
                      float* __restrict__ dinv, float4* __restrict__ xs,
                      int* __restrict__ wincur, int n, int nper) {
    int i = blockIdx.x * 256 + threadIdx.x;
    int lane = threadIdx.x & 63;
    int d = (i < n) ? deg[i] : 0;
    int win = (i < n) ? (i / nper) : (NWIN - 1);
    int p = d;
    #pragma unroll
    for (int o = 1; o < 64; o <<= 1) {
        int v = __shfl_up(p, o);
        if (lane >= o) p += v;
    }
    int base = 0;
    if (lane == 63) base = atomicAdd(&wincur[win], p);
    base = __shfl(base, 63);
    int my = base + p - d;
    if (i < n) {
        off[i] = my; cursor[i] = my;
        float di = rsqrtf((float)(d + 1));
        dinv[i] = di;
        xs[i] = make_float4(x[i * 3 + 0] * di, x[i * 3 + 1] * di, x[i * 3 + 2] * di, di);
    }
}

// windowed CSR fill
__global__ __launch_bounds__(256) void k_fill(const int* __restrict__ src,
                                              const int* __restrict__ dst,
                                              int* __restrict__ cursor,
                                              int* __restrict__ csr, int E, int nper) {
    int win = blockIdx.x & (NWIN - 1);
    int nblk = gridDim.x >> 3;
    int bw = blockIdx.x >> 3;
    int lo = win * nper, hi = lo + nper;
    for (int e = bw * 256 + threadIdx.x; e < E; e += nblk * 256) {
        int d = dst[e];
        if (d >= lo && d < hi) {
            int p = atomicAdd(&cursor[d], 1);
            csr[p] = src[e];
        }
    }
}

// conv1 aggregation on 3-dim raw features: one THREAD per node, 4x unrolled.
__global__ void k_agg1(const float4* __restrict__ xs, const int* __restrict__ off,
                       const int* __restrict__ deg, const int* __restrict__ csr,
                       float4* __restrict__ agg1, int n) {
    int i = blockIdx.x * 256 + threadIdx.x;
    if (i >= n) return;
    int e0 = off[i], e1 = e0 + deg[i];
    float sx = 0.f, sy = 0.f, sz = 0.f;
    int e = e0;
    for (; e + 4 <= e1; e += 4) {
        int s0 = csr[e], s1 = csr[e + 1], s2 = csr[e + 2], s3 = csr[e + 3];
        float4 v0 = xs[s0], v1 = xs[s1], v2 = xs[s2], v3 = xs[s3];
        sx += v0.x + v1.x + v2.x + v3.x;
        sy += v0.y + v1.y + v2.y + v3.y;
        sz += v0.z + v1.z + v2.z + v3.z;
    }
    for (; e < e1; ++e) {
        float4 v = xs[csr[e]];
        sx += v.x; sy += v.y; sz += v.z;
    }
    float4 self = xs[i];
    float di = self.w;
    agg1[i] = make_float4((sx + self.x) * di, (sy + self.y) * di, (sz + self.z) * di, di);
}

// h1s[i] = bf16( relu(agg1[i].xyz @ W1 + b1) * dinv )
__global__ __launch_bounds__(256) void k_h1(const float4* __restrict__ agg1,
                                            const float* __restrict__ W1,
                                            const float* __restrict__ b1,
                                            unsigned short* __restrict__ h1s, int n) {
    int wv = threadIdx.x >> 6;
    int lane = threadIdx.x & 63;
    int i = blockIdx.x * 4 + wv;
    if (i >= n) return;
    int c0 = lane * 2;
    float4 a = agg1[i];
    float h0 = fmaxf(a.x * W1[0 * HID + c0]     + a.y * W1[1 * HID + c0]     + a.z * W1[2 * HID + c0]     + b1[c0],     0.f) * a.w;
    float h1 = fmaxf(a.x * W1[0 * HID + c0 + 1] + a.y * W1[1 * HID + c0 + 1] + a.z * W1[2 * HID + c0 + 1] + b1[c0 + 1], 0.f) * a.w;
    ushort2 pk;
    pk.x = f2bf(h0);
    pk.y = f2bf(h1);
    *(ushort2*)&h1s[(size_t)i * HID + c0] = pk;
}

// conv2 aggregation over bf16 rows; OUTPUT bf16 g2s (A-operand for the MFMA GEMM).
__global__ __launch_bounds__(256) void k_agg2(const unsigned short* __restrict__ h1s,
                                              const float* __restrict__ dinv,
                                              const int* __restrict__ off,
                                              const int* __restrict__ deg,
                                              const int* __restrict__ csr,
                                              unsigned short* __restrict__ g2s, int n) {
    int wv = threadIdx.x >> 6;
    int lane = threadIdx.x & 63;
    int half = lane >> 5;
    int col = lane & 31;
    int node = blockIdx.x * 4 + wv;
    if (node >= n) return;
    int e0 = off[node], e1 = e0 + deg[node];
    float ax = 0.f, ay = 0.f, az = 0.f, aw = 0.f;

    for (int base = e0; base < e1; base += 64) {
        int m = e1 - base; if (m > 64) m = 64;
        int idx = (base + lane < e1) ? csr[base + lane] : 0;
        int j = 0;
        for (; j + 8 <= m; j += 8) {
            int s0 = __shfl(idx, j + 0 + half);
            int s1 = __shfl(idx, j + 2 + half);
            int s2 = __shfl(idx, j + 4 + half);
            int s3 = __shfl(idx, j + 6 + half);
            uint2 r0 = *(const uint2*)&h1s[(size_t)s0 * HID + col * 4];
            uint2 r1 = *(const uint2*)&h1s[(size_t)s1 * HID + col * 4];
            uint2 r2 = *(const uint2*)&h1s[(size_t)s2 * HID + col * 4];
            uint2 r3 = *(const uint2*)&h1s[(size_t)s3 * HID + col * 4];
            ax += bflo(r0.x) + bflo(r1.x) + bflo(r2.x) + bflo(r3.x);
            ay += bfhi(r0.x) + bfhi(r1.x) + bfhi(r2.x) + bfhi(r3.x);
            az += bflo(r0.y) + bflo(r1.y) + bflo(r2.y) + bflo(r3.y);
            aw += bfhi(r0.y) + bfhi(r1.y) + bfhi(r2.y) + bfhi(r3.y);
        }
        for (; j < m; j += 2) {
            int jj = j + half;
            if (jj < m) {
                int s = __shfl(idx, jj);
                uint2 r = *(const uint2*)&h1s[(size_t)s * HID + col * 4];
                ax += bflo(r.x); ay += bfhi(r.x);
                az += bflo(r.y); aw += bfhi(r.y);
            }
        }
    }
    ax += __shfl_down(ax, 32);
    ay += __shfl_down(ay, 32);
    az += __shfl_down(az, 32);
    aw += __shfl_down(aw, 32);

    if (half == 0) {
        uint2 r = *(const uint2*)&h1s[(size_t)node * HID + col * 4];
        float di = dinv[node];
        ushort4 pk;
        pk.x = f2bf((ax + bflo(r.x)) * di);
        pk.y = f2bf((ay + bfhi(r.x)) * di);
        pk.z = f2bf((az + bflo(r.y)) * di);
        pk.w = f2bf((aw + bfhi(r.y)) * di);
        *(ushort4*)&g2s[(size_t)node * HID + col * 4] = pk;
    }
}

// MFMA GEMM: h2 = relu(g2s @ W2 + b2); pool += sum_rows h2 . Wf   (no LDS, no barrier)
// 64 rows/block, 4 waves x 16 rows; 16x16x32_bf16; A row=l&15, k=(l>>4)*8+j; B from W2T.
__global__ __launch_bounds__(256) void k_gemm2m(const unsigned short* __restrict__ g2s,
                                                const unsigned short* __restrict__ W2T,
                                                const float* __restrict__ b2,
                                                const float* __restrict__ Wf,
                                                float* __restrict__ pool, int n) {
    int tid = threadIdx.x;
    int wv = tid >> 6;
    int lane = tid & 63;
    int r0 = blockIdx.x * 64 + wv * 16;
    int arow = r0 + (lane & 15);
    int koff = (lane >> 4) * 8;

    f32x4 acc[8];
    #pragma unroll
    for (int ct = 0; ct < 8; ++ct) acc[ct] = (f32x4){0.f, 0.f, 0.f, 0.f};

    #pragma unroll
    for (int kk = 0; kk < 4; ++kk) {
        bf16x8 af = *(const bf16x8*)&g2s[(size_t)arow * HID + kk * 32 + koff];
        #pragma unroll
        for (int ct = 0; ct < 8; ++ct) {
            bf16x8 bfg = *(const bf16x8*)&W2T[(size_t)(ct * 16 + (lane & 15)) * HID + kk * 32 + koff];
            acc[ct] = __builtin_amdgcn_mfma_f32_16x16x32_bf16(af, bfg, acc[ct], 0, 0, 0);
        }
    }

    float d = 0.f;
    #pragma unroll
    for (int ct = 0; ct < 8; ++ct) {
        int col = ct * 16 + (lane & 15);
        float b2v = b2[col];
        float wfv = Wf[col];
        #pragma unroll
        for (int q = 0; q < 4; ++q) {
            int row = r0 + (lane >> 4) * 4 + q;
            if (row < n) {
                float h = fmaxf(acc[ct][q] + b2v, 0.f);
                d += h * wfv;
            }
        }
    }
    #pragma unroll
    for (int o = 32; o > 0; o >>= 1) d += __shfl_down(d, o);
    if (lane == 0) atomicAdd(pool, d);
}

__global__ void k_final(const float* __restrict__ pool, const float* __restrict__ bf,
                        float* __restrict__ out, float invn) {
    if (threadIdx.x == 0 && blockIdx.x == 0) out[0] = pool[0] * invn + bf[0];
}

extern "C" void kernel_launch(void* const* d_in, const int* in_sizes, int n_in,
                              void* d_out, int out_size, void* d_ws, size_t ws_size,
                              hipStream_t stream) {
    const float* x  = (const float*)d_in[0];
    const int*   ei = (const int*)d_in[1];
    const float* W1 = (const float*)d_in[2];
    const float* b1 = (const float*)d_in[3];
    const float* W2 = (const float*)d_in[4];
    const float* b2 = (const float*)d_in[5];
    const float* Wf = (const float*)d_in[6];
    const float* bf = (const float*)d_in[7];
    int n = in_sizes[0] / 3;
    int E = in_sizes[1] / 2;
    const int* src = ei;
    const int* dst = ei + E;
    int nper = ((n + NWIN - 1) / NWIN + 63) & ~63;

    char* w = (char*)d_ws;
    int*    deg    = (int*)(w + 0);                    // 400KB
    int*    off    = (int*)(w + (512ll << 10));        // 400KB
    int*    cursor = (int*)(w + (1024ll << 10));       // 400KB
    float*  dinv   = (float*)(w + (1536ll << 10));     // 400KB
    float*  pool   = (float*)(w + (2048ll << 10));     // 4B
    int*    wintot = (int*)(w + (2048ll << 10) + 128); // 32B
    int*    wincur = (int*)(w + (2048ll << 10) + 256); // 32B
    int*    csr    = (int*)(w + (2560ll << 10));       // 6.4MB
    float4* xs     = (float4*)(w + (9ll << 20));       // 1.6MB
    float4* agg1   = (float4*)(w + (11ll << 20));      // 1.6MB
    unsigned short* h1s = (unsigned short*)(w + (13ll << 20)); // 25.6MB
    unsigned short* g2s = (unsigned short*)(w + (39ll << 20)); // 25.6MB (padded rows)
    unsigned short* W2T = (unsigned short*)(w + (66ll << 20)); // 32KB

    hipMemsetAsync(deg, 0, (size_t)n * sizeof(int), stream);
    hipMemsetAsync(pool, 0, 512, stream);

    k_w2t<<<(HID * HID + 255) / 256, 256, 0, stream>>>(W2, W2T);
    k_deg<<<(E + 255) / 256, 256, 0, stream>>>(dst, deg, wintot, E, nper);
    k_winscan<<<1, 64, 0, stream>>>(wintot, wincur);
    k_off<<<(n + 255) / 256, 256, 0, stream>>>(deg, x, off, cursor, dinv, xs, wincur, n, nper);
    k_fill<<<1024, 256, 0, stream>>>(src, dst, cursor, csr, E, nper);

    k_agg1<<<(n + 255) / 256, 256, 0, stream>>>(xs, off, deg, csr, agg1, n);
    k_h1<<<(n + 3) / 4, 256, 0, stream>>>(agg1, W1, b1, h1s, n);
    k_agg2<<<(n + 3) / 4, 256, 0, stream>>>(h1s, dinv, off, deg, csr, g2s, n);
    k_gemm2m<<<(n + 63) / 64, 256, 0, stream>>>(g2s, W2T, b2, Wf, pool, n);
    k_final<<<1, 64, 0, stream>>>(pool, bf, (float*)d_out, 1.0f / (float)n);
}

// Round 13
// 373.905 us; speedup vs baseline: 8.3350x; 1.2303x over previous
//
#include <hip/hip_runtime.h>
#include <hip/hip_bf16.h>
#include <cstdint>
#include <cstddef>

// GCN restructured:
//   conv1: agg RAW 3-dim features, W1 AFTER agg.  conv2: agg bf16 h1s rows -> bf16 g2s,
//   then MFMA bf16 GEMM (g2s @ W2) with relu+Wf+pool fused; block partials (NO
//   same-address atomics) + W2T staged in LDS (padded rows, 2-way max aliasing).
// CSR build is dst-WINDOWED (8 windows via blockIdx&7) for L2-local scatter.

#define HID 128
#define NWIN 8

typedef short bf16x8 __attribute__((ext_vector_type(8)));
typedef float f32x4 __attribute__((ext_vector_type(4)));

__device__ inline float bflo(unsigned u) { return __uint_as_float(u << 16); }
__device__ inline float bfhi(unsigned u) { return __uint_as_float(u & 0xffff0000u); }
__device__ inline unsigned short f2bf(float f) {
    __hip_bfloat16 q = __float2bfloat16(f);
    return *(unsigned short*)&q;
}

// degree count + per-window edge histogram
__global__ void k_deg(const int* __restrict__ dst, int* __restrict__ deg,
                      int* __restrict__ wintot, int E, int nper) {
    __shared__ int h[NWIN];
    if (threadIdx.x < NWIN) h[threadIdx.x] = 0;
    __syncthreads();
    int e = blockIdx.x * 256 + threadIdx.x;
    if (e < E) {
        int d = dst[e];
        atomicAdd(&deg[d], 1);
        atomicAdd(&h[d / nper], 1);
    }
    __syncthreads();
    if (threadIdx.x < NWIN) atomicAdd(&wintot[threadIdx.x], h[threadIdx.x]);
}

__global__ void k_winscan(const int* __restrict__ wintot, int* __restrict__ wincur) {
    int t = threadIdx.x;
    int v = (t < NWIN) ? wintot[t] : 0;
    int p = v;
    #pragma unroll
    for (int o = 1; o < NWIN; o <<= 1) {
        int u = __shfl_up(p, o);
        if (t >= o) p += u;
    }
    if (t < NWIN) wincur[t] = p - v;
}

// W2T[c][k] = bf16(W2[k][c])  (32KB, built once, L2-resident)
__global__ void k_w2t(const float* __restrict__ W2, unsigned short* __restrict__ W2T) {
    int i = blockIdx.x * 256 + threadIdx.x;
    if (i < HID * HID) {
        int k = i >> 7, c = i & 127;
        W2T[c * HID + k] = f2bf(W2[k * HID + c]);
    }
}

// node range start within its window (order-free, one atomic per wave);
// also dinv[i] and xs[i] = {x*dinv, dinv}.
__global__ void k_off(const int* __restrict__ deg, const float* __restrict__ x,
                      int* __restrict__ off, int* __restrict__ cursor,
                      float* __restrict__ dinv, float4* __restrict__ xs,
                      int* __restrict__ wincur, int n, int nper) {
    int i = blockIdx.x * 256 + threadIdx.x;
    int lane = threadIdx.x & 63;
    int d = (i < n) ? deg[i] : 0;
    int win = (i < n) ? (i / nper) : (NWIN - 1);
    int p = d;
    #pragma unroll
    for (int o = 1; o < 64; o <<= 1) {
        int v = __shfl_up(p, o);
        if (lane >= o) p += v;
    }
    int base = 0;
    if (lane == 63) base = atomicAdd(&wincur[win], p);
    base = __shfl(base, 63);
    int my = base + p - d;
    if (i < n) {
        off[i] = my; cursor[i] = my;
        float di = rsqrtf((float)(d + 1));
        dinv[i] = di;
        xs[i] = make_float4(x[i * 3 + 0] * di, x[i * 3 + 1] * di, x[i * 3 + 2] * di, di);
    }
}

// windowed CSR fill
__global__ __launch_bounds__(256) void k_fill(const int* __restrict__ src,
                                              const int* __restrict__ dst,
                                              int* __restrict__ cursor,
                                              int* __restrict__ csr, int E, int nper) {
    int win = blockIdx.x & (NWIN - 1);
    int nblk = gridDim.x >> 3;
    int bw = blockIdx.x >> 3;
    int lo = win * nper, hi = lo + nper;
    for (int e = bw * 256 + threadIdx.x; e < E; e += nblk * 256) {
        int d = dst[e];
        if (d >= lo && d < hi) {
            int p = atomicAdd(&cursor[d], 1);
            csr[p] = src[e];
        }
    }
}

// conv1 aggregation on 3-dim raw features: one THREAD per node, 4x unrolled.
__global__ void k_agg1(const float4* __restrict__ xs, const int* __restrict__ off,
                       const int* __restrict__ deg, const int* __restrict__ csr,
                       float4* __restrict__ agg1, int n) {
    int i = blockIdx.x * 256 + threadIdx.x;
    if (i >= n) return;
    int e0 = off[i], e1 = e0 + deg[i];
    float sx = 0.f, sy = 0.f, sz = 0.f;
    int e = e0;
    for (; e + 4 <= e1; e += 4) {
        int s0 = csr[e], s1 = csr[e + 1], s2 = csr[e + 2], s3 = csr[e + 3];
        float4 v0 = xs[s0], v1 = xs[s1], v2 = xs[s2], v3 = xs[s3];
        sx += v0.x + v1.x + v2.x + v3.x;
        sy += v0.y + v1.y + v2.y + v3.y;
        sz += v0.z + v1.z + v2.z + v3.z;
    }
    for (; e < e1; ++e) {
        float4 v = xs[csr[e]];
        sx += v.x; sy += v.y; sz += v.z;
    }
    float4 self = xs[i];
    float di = self.w;
    agg1[i] = make_float4((sx + self.x) * di, (sy + self.y) * di, (sz + self.z) * di, di);
}

// h1s[i] = bf16( relu(agg1[i].xyz @ W1 + b1) * dinv )
__global__ __launch_bounds__(256) void k_h1(const float4* __restrict__ agg1,
                                            const float* __restrict__ W1,
                                            const float* __restrict__ b1,
                                            unsigned short* __restrict__ h1s, int n) {
    int wv = threadIdx.x >> 6;
    int lane = threadIdx.x & 63;
    int i = blockIdx.x * 4 + wv;
    if (i >= n) return;
    int c0 = lane * 2;
    float4 a = agg1[i];
    float h0 = fmaxf(a.x * W1[0 * HID + c0]     + a.y * W1[1 * HID + c0]     + a.z * W1[2 * HID + c0]     + b1[c0],     0.f) * a.w;
    float h1 = fmaxf(a.x * W1[0 * HID + c0 + 1] + a.y * W1[1 * HID + c0 + 1] + a.z * W1[2 * HID + c0 + 1] + b1[c0 + 1], 0.f) * a.w;
    ushort2 pk;
    pk.x = f2bf(h0);
    pk.y = f2bf(h1);
    *(ushort2*)&h1s[(size_t)i * HID + c0] = pk;
}

// conv2 aggregation over bf16 rows; OUTPUT bf16 g2s (A-operand for the MFMA GEMM).
__global__ __launch_bounds__(256) void k_agg2(const unsigned short* __restrict__ h1s,
                                              const float* __restrict__ dinv,
                                              const int* __restrict__ off,
                                              const int* __restrict__ deg,
                                              const int* __restrict__ csr,
                                              unsigned short* __restrict__ g2s, int n) {
    int wv = threadIdx.x >> 6;
    int lane = threadIdx.x & 63;
    int half = lane >> 5;
    int col = lane & 31;
    int node = blockIdx.x * 4 + wv;
    if (node >= n) return;
    int e0 = off[node], e1 = e0 + deg[node];
    float ax = 0.f, ay = 0.f, az = 0.f, aw = 0.f;

    for (int base = e0; base < e1; base += 64) {
        int m = e1 - base; if (m > 64) m = 64;
        int idx = (base + lane < e1) ? csr[base + lane] : 0;
        int j = 0;
        for (; j + 8 <= m; j += 8) {
            int s0 = __shfl(idx, j + 0 + half);
            int s1 = __shfl(idx, j + 2 + half);
            int s2 = __shfl(idx, j + 4 + half);
            int s3 = __shfl(idx, j + 6 + half);
            uint2 r0 = *(const uint2*)&h1s[(size_t)s0 * HID + col * 4];
            uint2 r1 = *(const uint2*)&h1s[(size_t)s1 * HID + col * 4];
            uint2 r2 = *(const uint2*)&h1s[(size_t)s2 * HID + col * 4];
            uint2 r3 = *(const uint2*)&h1s[(size_t)s3 * HID + col * 4];
            ax += bflo(r0.x) + bflo(r1.x) + bflo(r2.x) + bflo(r3.x);
            ay += bfhi(r0.x) + bfhi(r1.x) + bfhi(r2.x) + bfhi(r3.x);
            az += bflo(r0.y) + bflo(r1.y) + bflo(r2.y) + bflo(r3.y);
            aw += bfhi(r0.y) + bfhi(r1.y) + bfhi(r2.y) + bfhi(r3.y);
        }
        for (; j < m; j += 2) {
            int jj = j + half;
            if (jj < m) {
                int s = __shfl(idx, jj);
                uint2 r = *(const uint2*)&h1s[(size_t)s * HID + col * 4];
                ax += bflo(r.x); ay += bfhi(r.x);
                az += bflo(r.y); aw += bfhi(r.y);
            }
        }
    }
    ax += __shfl_down(ax, 32);
    ay += __shfl_down(ay, 32);
    az += __shfl_down(az, 32);
    aw += __shfl_down(aw, 32);

    if (half == 0) {
        uint2 r = *(const uint2*)&h1s[(size_t)node * HID + col * 4];
        float di = dinv[node];
        ushort4 pk;
        pk.x = f2bf((ax + bflo(r.x)) * di);
        pk.y = f2bf((ay + bfhi(r.x)) * di);
        pk.z = f2bf((az + bflo(r.y)) * di);
        pk.w = f2bf((aw + bfhi(r.y)) * di);
        *(ushort4*)&g2s[(size_t)node * HID + col * 4] = pk;
    }
}

// MFMA GEMM: h2 = relu(g2s @ W2 + b2); part[block] = sum_rows h2 . Wf
// W2T staged in LDS (row pad +8 ushort => 2-way max bank aliasing, free).
// Per-block partial: NO same-address global atomics.
__global__ __launch_bounds__(256) void k_gemm2m(const unsigned short* __restrict__ g2s,
                                                const unsigned short* __restrict__ W2T,
                                                const float* __restrict__ b2,
                                                const float* __restrict__ Wf,
                                                float* __restrict__ part, int n) {
    __shared__ unsigned short ldsB[HID][HID + 8];   // 34.8KB, 272B rows
    __shared__ float sbp[4];
    int tid = threadIdx.x;
    int wv = tid >> 6;
    int lane = tid & 63;

    // stage W2T: 128 rows x 16 chunks of 16B; 8 chunks per thread
    #pragma unroll
    for (int q = 0; q < 8; ++q) {
        int id = tid + q * 256;
        int row = id >> 4, ch = id & 15;
        *(uint4*)&ldsB[row][ch * 8] = *(const uint4*)&W2T[(size_t)row * HID + ch * 8];
    }
    __syncthreads();

    int r0 = blockIdx.x * 64 + wv * 16;
    int arow = r0 + (lane & 15);
    int koff = (lane >> 4) * 8;

    // hoist all 4 A fragments: independent global loads
    bf16x8 af[4];
    #pragma unroll
    for (int kk = 0; kk < 4; ++kk)
        af[kk] = *(const bf16x8*)&g2s[(size_t)arow * HID + kk * 32 + koff];

    f32x4 acc[8];
    #pragma unroll
    for (int ct = 0; ct < 8; ++ct) acc[ct] = (f32x4){0.f, 0.f, 0.f, 0.f};

    #pragma unroll
    for (int kk = 0; kk < 4; ++kk) {
        #pragma unroll
        for (int ct = 0; ct < 8; ++ct) {
            bf16x8 bfr = *(const bf16x8*)&ldsB[ct * 16 + (lane & 15)][kk * 32 + koff];
            acc[ct] = __builtin_amdgcn_mfma_f32_16x16x32_bf16(af[kk], bfr, acc[ct], 0, 0, 0);
        }
    }

    float d = 0.f;
    #pragma unroll
    for (int ct = 0; ct < 8; ++ct) {
        int col = ct * 16 + (lane & 15);
        float b2v = b2[col];
        float wfv = Wf[col];
        #pragma unroll
        for (int q = 0; q < 4; ++q) {
            int row = r0 + (lane >> 4) * 4 + q;
            if (row < n) {
                float h = fmaxf(acc[ct][q] + b2v, 0.f);
                d += h * wfv;
            }
        }
    }
    #pragma unroll
    for (int o = 32; o > 0; o >>= 1) d += __shfl_down(d, o);
    if (lane == 0) sbp[wv] = d;
    __syncthreads();
    if (tid == 0) part[blockIdx.x] = sbp[0] + sbp[1] + sbp[2] + sbp[3];
}

// reduce block partials + bias
__global__ void k_final2(const float* __restrict__ part, int npart,
                         const float* __restrict__ bf, float* __restrict__ out,
                         float invn) {
    __shared__ float sb[256];
    float s = 0.f;
    for (int i = threadIdx.x; i < npart; i += 256) s += part[i];
    sb[threadIdx.x] = s;
    __syncthreads();
    for (int o = 128; o > 0; o >>= 1) {
        if (threadIdx.x < o) sb[threadIdx.x] += sb[threadIdx.x + o];
        __syncthreads();
    }
    if (threadIdx.x == 0) out[0] = sb[0] * invn + bf[0];
}

extern "C" void kernel_launch(void* const* d_in, const int* in_sizes, int n_in,
                              void* d_out, int out_size, void* d_ws, size_t ws_size,
                              hipStream_t stream) {
    const float* x  = (const float*)d_in[0];
    const int*   ei = (const int*)d_in[1];
    const float* W1 = (const float*)d_in[2];
    const float* b1 = (const float*)d_in[3];
    const float* W2 = (const float*)d_in[4];
    const float* b2 = (const float*)d_in[5];
    const float* Wf = (const float*)d_in[6];
    const float* bf = (const float*)d_in[7];
    int n = in_sizes[0] / 3;
    int E = in_sizes[1] / 2;
    const int* src = ei;
    const int* dst = ei + E;
    int nper = ((n + NWIN - 1) / NWIN + 63) & ~63;
    int npart = (n + 63) / 64;

    char* w = (char*)d_ws;
    int*    deg    = (int*)(w + 0);                    // 400KB
    int*    off    = (int*)(w + (512ll << 10));        // 400KB
    int*    cursor = (int*)(w + (1024ll << 10));       // 400KB
    float*  dinv   = (float*)(w + (1536ll << 10));     // 400KB
    int*    wintot = (int*)(w + (2048ll << 10) + 128); // 32B
    int*    wincur = (int*)(w + (2048ll << 10) + 256); // 32B
    int*    csr    = (int*)(w + (2560ll << 10));       // 6.4MB
    float4* xs     = (float4*)(w + (9ll << 20));       // 1.6MB
    float4* agg1   = (float4*)(w + (11ll << 20));      // 1.6MB
    unsigned short* h1s = (unsigned short*)(w + (13ll << 20)); // 25.6MB
    unsigned short* g2s = (unsigned short*)(w + (39ll << 20)); // 25.6MB
    unsigned short* W2T = (unsigned short*)(w + (66ll << 20)); // 32KB
    float*  part   = (float*)(w + (67ll << 20));       // 6.3KB

    hipMemsetAsync(deg, 0, (size_t)n * sizeof(int), stream);
    hipMemsetAsync(wintot, 0, 256, stream);

    k_w2t<<<(HID * HID + 255) / 256, 256, 0, stream>>>(W2, W2T);
    k_deg<<<(E + 255) / 256, 256, 0, stream>>>(dst, deg, wintot, E, nper);
    k_winscan<<<1, 64, 0, stream>>>(wintot, wincur);
    k_off<<<(n + 255) / 256, 256, 0, stream>>>(deg, x, off, cursor, dinv, xs, wincur, n, nper);
    k_fill<<<1024, 256, 0, stream>>>(src, dst, cursor, csr, E, nper);

    k_agg1<<<(n + 255) / 256, 256, 0, stream>>>(xs, off, deg, csr, agg1, n);
    k_h1<<<(n + 3) / 4, 256, 0, stream>>>(agg1, W1, b1, h1s, n);
    k_agg2<<<(n + 3) / 4, 256, 0, stream>>>(h1s, dinv, off, deg, csr, g2s, n);
    k_gemm2m<<<npart, 256, 0, stream>>>(g2s, W2T, b2, Wf, part, n);
    k_final2<<<1, 256, 0, stream>>>(part, npart, bf, (float*)d_out, 1.0f / (float)n);
}

// Round 15
// 348.747 us; speedup vs baseline: 8.9363x; 1.0721x over previous
//
#include <hip/hip_runtime.h>
#include <hip/hip_bf16.h>
#include <cstdint>
#include <cstddef>

// GCN restructured:
//   conv1: agg RAW 3-dim features, W1 AFTER agg.  conv2: agg bf16 h1s rows -> bf16 g2s,
//   then MFMA bf16 GEMM (g2s @ W2) with relu+Wf+pool fused; block partials + LDS-staged W2T.
// BOTH scatter-atomic kernels (k_deg, k_fill) are dst-WINDOWED (8 windows via blockIdx&7)
// so their atomics stay XCD-L2-local (cross-XCD line ping-pong was 50-105MB of HBM traffic).

#define HID 128
#define NWIN 8

typedef short bf16x8 __attribute__((ext_vector_type(8)));
typedef float f32x4 __attribute__((ext_vector_type(4)));

__device__ inline float bflo(unsigned u) { return __uint_as_float(u << 16); }
__device__ inline float bfhi(unsigned u) { return __uint_as_float(u & 0xffff0000u); }
__device__ inline unsigned short f2bf(float f) {
    __hip_bfloat16 q = __float2bfloat16(f);
    return *(unsigned short*)&q;
}

// windowed degree count: window = blockIdx&7; deg atomics stay in one XCD's L2.
// Per-block window-edge count -> wintot with ONE atomic per block.
__global__ __launch_bounds__(256) void k_deg(const int* __restrict__ dst,
                                             int* __restrict__ deg,
                                             int* __restrict__ wintot, int E, int nper) {
    __shared__ int sb[4];
    int win = blockIdx.x & (NWIN - 1);
    int nblk = gridDim.x >> 3;
    int bw = blockIdx.x >> 3;
    int lo = win * nper, hi = lo + nper;
    int cnt = 0;
    for (int e = bw * 256 + threadIdx.x; e < E; e += nblk * 256) {
        int d = dst[e];
        if (d >= lo && d < hi) {
            atomicAdd(&deg[d], 1);
            ++cnt;
        }
    }
    #pragma unroll
    for (int o = 32; o > 0; o >>= 1) cnt += __shfl_down(cnt, o);
    int wv = threadIdx.x >> 6;
    if ((threadIdx.x & 63) == 0) sb[wv] = cnt;
    __syncthreads();
    if (threadIdx.x == 0) atomicAdd(&wintot[win], sb[0] + sb[1] + sb[2] + sb[3]);
}

__global__ void k_winscan(const int* __restrict__ wintot, int* __restrict__ wincur) {
    int t = threadIdx.x;
    int v = (t < NWIN) ? wintot[t] : 0;
    int p = v;
    #pragma unroll
    for (int o = 1; o < NWIN; o <<= 1) {
        int u = __shfl_up(p, o);
        if (t >= o) p += u;
    }
    if (t < NWIN) wincur[t] = p - v;
}

// W2T[c][k] = bf16(W2[k][c])  (32KB, built once, L2-resident)
__global__ void k_w2t(const float* __restrict__ W2, unsigned short* __restrict__ W2T) {
    int i = blockIdx.x * 256 + threadIdx.x;
    if (i < HID * HID) {
        int k = i >> 7, c = i & 127;
        W2T[c * HID + k] = f2bf(W2[k * HID + c]);
    }
}

// node range start within its window (order-free, one atomic per wave);
// also dinv[i] and xs[i] = {x*dinv, dinv}.
__global__ void k_off(const int* __restrict__ deg, const float* __restrict__ x,
                      int* __restrict__ off, int* __restrict__ cursor,
                      float* __restrict__ dinv, float4* __restrict__ xs,
                      int* __restrict__ wincur, int n, int nper) {
    int i = blockIdx.x * 256 + threadIdx.x;
    int lane = threadIdx.x & 63;
    int d = (i < n) ? deg[i] : 0;
    int win = (i < n) ? (i / nper) : (NWIN - 1);
    int p = d;
    #pragma unroll
    for (int o = 1; o < 64; o <<= 1) {
        int v = __shfl_up(p, o);
        if (lane >= o) p += v;
    }
    int base = 0;
    if (lane == 63) base = atomicAdd(&wincur[win], p);
    base = __shfl(base, 63);
    int my = base + p - d;
    if (i < n) {
        off[i] = my; cursor[i] = my;
        float di = rsqrtf((float)(d + 1));
        dinv[i] = di;
        xs[i] = make_float4(x[i * 3 + 0] * di, x[i * 3 + 1] * di, x[i * 3 + 2] * di, di);
    }
}

// windowed CSR fill
__global__ __launch_bounds__(256) void k_fill(const int* __restrict__ src,
                                              const int* __restrict__ dst,
                                              int* __restrict__ cursor,
                                              int* __restrict__ csr, int E, int nper) {
    int win = blockIdx.x & (NWIN - 1);
    int nblk = gridDim.x >> 3;
    int bw = blockIdx.x >> 3;
    int lo = win * nper, hi = lo + nper;
    for (int e = bw * 256 + threadIdx.x; e < E; e += nblk * 256) {
        int d = dst[e];
        if (d >= lo && d < hi) {
            int p = atomicAdd(&cursor[d], 1);
            csr[p] = src[e];
        }
    }
}

// conv1 aggregation on 3-dim raw features: one THREAD per node, 4x unrolled.
__global__ void k_agg1(const float4* __restrict__ xs, const int* __restrict__ off,
                       const int* __restrict__ deg, const int* __restrict__ csr,
                       float4* __restrict__ agg1, int n) {
    int i = blockIdx.x * 256 + threadIdx.x;
    if (i >= n) return;
    int e0 = off[i], e1 = e0 + deg[i];
    float sx = 0.f, sy = 0.f, sz = 0.f;
    int e = e0;
    for (; e + 4 <= e1; e += 4) {
        int s0 = csr[e], s1 = csr[e + 1], s2 = csr[e + 2], s3 = csr[e + 3];
        float4 v0 = xs[s0], v1 = xs[s1], v2 = xs[s2], v3 = xs[s3];
        sx += v0.x + v1.x + v2.x + v3.x;
        sy += v0.y + v1.y + v2.y + v3.y;
        sz += v0.z + v1.z + v2.z + v3.z;
    }
    for (; e < e1; ++e) {
        float4 v = xs[csr[e]];
        sx += v.x; sy += v.y; sz += v.z;
    }
    float4 self = xs[i];
    float di = self.w;
    agg1[i] = make_float4((sx + self.x) * di, (sy + self.y) * di, (sz + self.z) * di, di);
}

// h1s[i] = bf16( relu(agg1[i].xyz @ W1 + b1) * dinv )
__global__ __launch_bounds__(256) void k_h1(const float4* __restrict__ agg1,
                                            const float* __restrict__ W1,
                                            const float* __restrict__ b1,
                                            unsigned short* __restrict__ h1s, int n) {
    int wv = threadIdx.x >> 6;
    int lane = threadIdx.x & 63;
    int i = blockIdx.x * 4 + wv;
    if (i >= n) return;
    int c0 = lane * 2;
    float4 a = agg1[i];
    float h0 = fmaxf(a.x * W1[0 * HID + c0]     + a.y * W1[1 * HID + c0]     + a.z * W1[2 * HID + c0]     + b1[c0],     0.f) * a.w;
    float h1 = fmaxf(a.x * W1[0 * HID + c0 + 1] + a.y * W1[1 * HID + c0 + 1] + a.z * W1[2 * HID + c0 + 1] + b1[c0 + 1], 0.f) * a.w;
    ushort2 pk;
    pk.x = f2bf(h0);
    pk.y = f2bf(h1);
    *(ushort2*)&h1s[(size_t)i * HID + c0] = pk;
}

// conv2 aggregation over bf16 rows; OUTPUT bf16 g2s (A-operand for the MFMA GEMM).
__global__ __launch_bounds__(256) void k_agg2(const unsigned short* __restrict__ h1s,
                                              const float* __restrict__ dinv,
                                              const int* __restrict__ off,
                                              const int* __restrict__ deg,
                                              const int* __restrict__ csr,
                                              unsigned short* __restrict__ g2s, int n) {
    int wv = threadIdx.x >> 6;
    int lane = threadIdx.x & 63;
    int half = lane >> 5;
    int col = lane & 31;
    int node = blockIdx.x * 4 + wv;
    if (node >= n) return;
    int e0 = off[node], e1 = e0 + deg[node];
    float ax = 0.f, ay = 0.f, az = 0.f, aw = 0.f;

    for (int base = e0; base < e1; base += 64) {
        int m = e1 - base; if (m > 64) m = 64;
        int idx = (base + lane < e1) ? csr[base + lane] : 0;
        int j = 0;
        for (; j + 8 <= m; j += 8) {
            int s0 = __shfl(idx, j + 0 + half);
            int s1 = __shfl(idx, j + 2 + half);
            int s2 = __shfl(idx, j + 4 + half);
            int s3 = __shfl(idx, j + 6 + half);
            uint2 r0 = *(const uint2*)&h1s[(size_t)s0 * HID + col * 4];
            uint2 r1 = *(const uint2*)&h1s[(size_t)s1 * HID + col * 4];
            uint2 r2 = *(const uint2*)&h1s[(size_t)s2 * HID + col * 4];
            uint2 r3 = *(const uint2*)&h1s[(size_t)s3 * HID + col * 4];
            ax += bflo(r0.x) + bflo(r1.x) + bflo(r2.x) + bflo(r3.x);
            ay += bfhi(r0.x) + bfhi(r1.x) + bfhi(r2.x) + bfhi(r3.x);
            az += bflo(r0.y) + bflo(r1.y) + bflo(r2.y) + bflo(r3.y);
            aw += bfhi(r0.y) + bfhi(r1.y) + bfhi(r2.y) + bfhi(r3.y);
        }
        for (; j < m; j += 2) {
            int jj = j + half;
            if (jj < m) {
                int s = __shfl(idx, jj);
                uint2 r = *(const uint2*)&h1s[(size_t)s * HID + col * 4];
                ax += bflo(r.x); ay += bfhi(r.x);
                az += bflo(r.y); aw += bfhi(r.y);
            }
        }
    }
    ax += __shfl_down(ax, 32);
    ay += __shfl_down(ay, 32);
    az += __shfl_down(az, 32);
    aw += __shfl_down(aw, 32);

    if (half == 0) {
        uint2 r = *(const uint2*)&h1s[(size_t)node * HID + col * 4];
        float di = dinv[node];
        ushort4 pk;
        pk.x = f2bf((ax + bflo(r.x)) * di);
        pk.y = f2bf((ay + bfhi(r.x)) * di);
        pk.z = f2bf((az + bflo(r.y)) * di);
        pk.w = f2bf((aw + bfhi(r.y)) * di);
        *(ushort4*)&g2s[(size_t)node * HID + col * 4] = pk;
    }
}

// MFMA GEMM: h2 = relu(g2s @ W2 + b2); part[block] = sum_rows h2 . Wf
__global__ __launch_bounds__(256) void k_gemm2m(const unsigned short* __restrict__ g2s,
                                                const unsigned short* __restrict__ W2T,
                                                const float* __restrict__ b2,
                                                const float* __restrict__ Wf,
                                                float* __restrict__ part, int n) {
    __shared__ unsigned short ldsB[HID][HID + 8];   // 34.8KB
    __shared__ float sbp[4];
    int tid = threadIdx.x;
    int wv = tid >> 6;
    int lane = tid & 63;

    #pragma unroll
    for (int q = 0; q < 8; ++q) {
        int id = tid + q * 256;
        int row = id >> 4, ch = id & 15;
        *(uint4*)&ldsB[row][ch * 8] = *(const uint4*)&W2T[(size_t)row * HID + ch * 8];
    }
    __syncthreads();

    int r0 = blockIdx.x * 64 + wv * 16;
    int arow = r0 + (lane & 15);
    int koff = (lane >> 4) * 8;

    bf16x8 af[4];
    #pragma unroll
    for (int kk = 0; kk < 4; ++kk)
        af[kk] = *(const bf16x8*)&g2s[(size_t)arow * HID + kk * 32 + koff];

    f32x4 acc[8];
    #pragma unroll
    for (int ct = 0; ct < 8; ++ct) acc[ct] = (f32x4){0.f, 0.f, 0.f, 0.f};

    #pragma unroll
    for (int kk = 0; kk < 4; ++kk) {
        #pragma unroll
        for (int ct = 0; ct < 8; ++ct) {
            bf16x8 bfr = *(const bf16x8*)&ldsB[ct * 16 + (lane & 15)][kk * 32 + koff];
            acc[ct] = __builtin_amdgcn_mfma_f32_16x16x32_bf16(af[kk], bfr, acc[ct], 0, 0, 0);
        }
    }

    float d = 0.f;
    #pragma unroll
    for (int ct = 0; ct < 8; ++ct) {
        int col = ct * 16 + (lane & 15);
        float b2v = b2[col];
        float wfv = Wf[col];
        #pragma unroll
        for (int q = 0; q < 4; ++q) {
            int row = r0 + (lane >> 4) * 4 + q;
            if (row < n) {
                float h = fmaxf(acc[ct][q] + b2v, 0.f);
                d += h * wfv;
            }
        }
    }
    #pragma unroll
    for (int o = 32; o > 0; o >>= 1) d += __shfl_down(d, o);
    if (lane == 0) sbp[wv] = d;
    __syncthreads();
    if (tid == 0) part[blockIdx.x] = sbp[0] + sbp[1] + sbp[2] + sbp[3];
}

// reduce block partials + bias
__global__ void k_final2(const float* __restrict__ part, int npart,
                         const float* __restrict__ bf, float* __restrict__ out,
                         float invn) {
    __shared__ float sb[256];
    float s = 0.f;
    for (int i = threadIdx.x; i < npart; i += 256) s += part[i];
    sb[threadIdx.x] = s;
    __syncthreads();
    for (int o = 128; o > 0; o >>= 1) {
        if (threadIdx.x < o) sb[threadIdx.x] += sb[threadIdx.x + o];
        __syncthreads();
    }
    if (threadIdx.x == 0) out[0] = sb[0] * invn + bf[0];
}

extern "C" void kernel_launch(void* const* d_in, const int* in_sizes, int n_in,
                              void* d_out, int out_size, void* d_ws, size_t ws_size,
                              hipStream_t stream) {
    const float* x  = (const float*)d_in[0];
    const int*   ei = (const int*)d_in[1];
    const float* W1 = (const float*)d_in[2];
    const float* b1 = (const float*)d_in[3];
    const float* W2 = (const float*)d_in[4];
    const float* b2 = (const float*)d_in[5];
    const float* Wf = (const float*)d_in[6];
    const float* bf = (const float*)d_in[7];
    int n = in_sizes[0] / 3;
    int E = in_sizes[1] / 2;
    const int* src = ei;
    const int* dst = ei + E;
    int nper = ((n + NWIN - 1) / NWIN + 63) & ~63;
    int npart = (n + 63) / 64;

    char* w = (char*)d_ws;
    int*    deg    = (int*)(w + 0);                    // 400KB
    int*    off    = (int*)(w + (512ll << 10));        // 400KB
    int*    cursor = (int*)(w + (1024ll << 10));       // 400KB
    float*  dinv   = (float*)(w + (1536ll << 10));     // 400KB
    int*    wintot = (int*)(w + (2048ll << 10) + 128); // 32B
    int*    wincur = (int*)(w + (2048ll << 10) + 256); // 32B
    int*    csr    = (int*)(w + (2560ll << 10));       // 6.4MB
    float4* xs     = (float4*)(w + (9ll << 20));       // 1.6MB
    float4* agg1   = (float4*)(w + (11ll << 20));      // 1.6MB
    unsigned short* h1s = (unsigned short*)(w + (13ll << 20)); // 25.6MB
    unsigned short* g2s = (unsigned short*)(w + (39ll << 20)); // 25.6MB
    unsigned short* W2T = (unsigned short*)(w + (66ll << 20)); // 32KB
    float*  part   = (float*)(w + (67ll << 20));       // 6.3KB

    hipMemsetAsync(deg, 0, (size_t)n * sizeof(int), stream);
    hipMemsetAsync(wintot, 0, 256, stream);

    k_w2t<<<(HID * HID + 255) / 256, 256, 0, stream>>>(W2, W2T);
    k_deg<<<1024, 256, 0, stream>>>(dst, deg, wintot, E, nper);
    k_winscan<<<1, 64, 0, stream>>>(wintot, wincur);
    k_off<<<(n + 255) / 256, 256, 0, stream>>>(deg, x, off, cursor, dinv, xs, wincur, n, nper);
    k_fill<<<1024, 256, 0, stream>>>(src, dst, cursor, csr, E, nper);

    k_agg1<<<(n + 255) / 256, 256, 0, stream>>>(xs, off, deg, csr, agg1, n);
    k_h1<<<(n + 3) / 4, 256, 0, stream>>>(agg1, W1, b1, h1s, n);
    k_agg2<<<(n + 3) / 4, 256, 0, stream>>>(h1s, dinv, off, deg, csr, g2s, n);
    k_gemm2m<<<npart, 256, 0, stream>>>(g2s, W2T, b2, Wf, part, n);
    k_final2<<<1, 256, 0, stream>>>(part, npart, bf, (float*)d_out, 1.0f / (float)n);
}